// Round 1
// baseline (286.755 us; speedup 1.0000x reference)
//
#include <hip/hip_runtime.h>

// Involution1d: B=16, CH=256, DIM=4096, G=16, GROUP=16, K=7, PAD=3, STRIDE=1
// hid = 64, K*G = 112.
#define BB   16
#define CHN  256
#define DIMN 4096
#define GG   16
#define GRPC 16
#define KK   7
#define PADK 3
#define HID  64
#define KGN  112
#define BN_EPS 1e-5f

// ---------------------------------------------------------------------------
// w1 (64 x 256, row = o) -> w1t (256 x 64, row = c) so kerngen can read
// weight rows as contiguous uniform scalar loads.
__global__ __launch_bounds__(256) void transpose_w1_k(
    const float* __restrict__ w1, float* __restrict__ w1t) {
    int t = blockIdx.x * 256 + threadIdx.x;   // 0 .. 16383
    int o = t & 63;
    int c = t >> 6;
    w1t[c * HID + o] = w1[o * CHN + c];
}

// ---------------------------------------------------------------------------
// Kernel generator: one thread per (b, l).  h = BN(relu(W1 x + b1)),
// kern[b, r, l] = W2 h + b2,  r in [0,112).
__global__ __launch_bounds__(256) void kerngen_k(
    const float* __restrict__ x,
    const float* __restrict__ w1t,   // [256][64]
    const float* __restrict__ b1,
    const float* __restrict__ bn_gamma,
    const float* __restrict__ bn_beta,
    const float* __restrict__ bn_mean,
    const float* __restrict__ bn_var,
    const float* __restrict__ w2,    // [112][64]
    const float* __restrict__ b2,
    float* __restrict__ kern) {      // [16][112][4096]
    int t = blockIdx.x * 256 + threadIdx.x;   // 0 .. 65535
    int b = t >> 12;                           // / 4096
    int l = t & 4095;

    const float* xb = x + (size_t)b * CHN * DIMN + l;

    float h[HID];
#pragma unroll
    for (int o = 0; o < HID; ++o) h[o] = b1[o];

    // h += W1 * x[:, l]   (software-pipelined x load; weights are uniform
    // scalar loads from the transposed copy)
    float xv = xb[0];
    for (int c = 0; c < CHN; ++c) {
        float xcur = xv;
        if (c + 1 < CHN) xv = xb[(size_t)(c + 1) * DIMN];
        const float* wrow = w1t + c * HID;
#pragma unroll
        for (int o = 0; o < HID; ++o) h[o] = fmaf(wrow[o], xcur, h[o]);
    }

    // relu + batchnorm (inference)
#pragma unroll
    for (int o = 0; o < HID; ++o) {
        float hv  = fmaxf(h[o], 0.0f);
        float inv = rsqrtf(bn_var[o] + BN_EPS);
        h[o] = (hv - bn_mean[o]) * inv * bn_gamma[o] + bn_beta[o];
    }

    // kern rows
    float* kb = kern + (size_t)b * KGN * DIMN + l;
    for (int r = 0; r < KGN; ++r) {
        const float* w2r = w2 + r * HID;
        float acc = b2[r];
#pragma unroll
        for (int hh = 0; hh < HID; ++hh) acc = fmaf(w2r[hh], h[hh], acc);
        kb[(size_t)r * DIMN] = acc;
    }
}

// ---------------------------------------------------------------------------
// Involution: out[b, g*16+c, l] = sum_k kern[b, g*7+k, l] * xpad[b, ch, l+k-3]
// One thread per (b, ch, 4 consecutive l).
__global__ __launch_bounds__(256) void involution_k(
    const float* __restrict__ x,
    const float* __restrict__ kern,
    float* __restrict__ out) {
    int t  = blockIdx.x * 256 + threadIdx.x;  // 0 .. 4,194,303
    int l4 = t & 1023;
    int ch = (t >> 10) & 255;
    int b  = t >> 18;
    int l  = l4 * 4;
    int g  = ch >> 4;

    const float* xrow = x + ((size_t)b * CHN + ch) * DIMN;

    float xr[10];
#pragma unroll
    for (int j = 0; j < 10; ++j) {
        int xi = l - PADK + j;
        xr[j] = ((unsigned)xi < (unsigned)DIMN) ? xrow[xi] : 0.0f;
    }

    const float* kb = kern + ((size_t)b * KGN + g * KK) * DIMN + l;

    float ox = 0.f, oy = 0.f, oz = 0.f, ow = 0.f;
#pragma unroll
    for (int k = 0; k < KK; ++k) {
        float4 kf = *(const float4*)(kb + (size_t)k * DIMN);
        ox = fmaf(kf.x, xr[k + 0], ox);
        oy = fmaf(kf.y, xr[k + 1], oy);
        oz = fmaf(kf.z, xr[k + 2], oz);
        ow = fmaf(kf.w, xr[k + 3], ow);
    }

    float4 o4 = make_float4(ox, oy, oz, ow);
    *(float4*)(out + ((size_t)b * CHN + ch) * DIMN + l) = o4;
}

// ---------------------------------------------------------------------------
extern "C" void kernel_launch(void* const* d_in, const int* in_sizes, int n_in,
                              void* d_out, int out_size, void* d_ws, size_t ws_size,
                              hipStream_t stream) {
    (void)in_sizes; (void)n_in; (void)out_size; (void)ws_size;

    const float* x        = (const float*)d_in[0];
    const float* w1       = (const float*)d_in[1];
    const float* b1       = (const float*)d_in[2];
    const float* bn_gamma = (const float*)d_in[3];
    const float* bn_beta  = (const float*)d_in[4];
    const float* bn_mean  = (const float*)d_in[5];
    const float* bn_var   = (const float*)d_in[6];
    const float* w2       = (const float*)d_in[7];
    const float* b2       = (const float*)d_in[8];
    float*       out      = (float*)d_out;

    float* w1t  = (float*)d_ws;                    // 256*64 floats = 64 KiB
    float* kern = (float*)d_ws + CHN * HID;        // 16*112*4096 floats = 28 MiB

    transpose_w1_k<<<(CHN * HID) / 256, 256, 0, stream>>>(w1, w1t);
    kerngen_k<<<(BB * DIMN) / 256, 256, 0, stream>>>(
        x, w1t, b1, bn_gamma, bn_beta, bn_mean, bn_var, w2, b2, kern);
    involution_k<<<(BB * CHN * (DIMN / 4)) / 256, 256, 0, stream>>>(x, kern, out);
}

// Round 2
// 137.238 us; speedup vs baseline: 2.0895x; 2.0895x over previous
//
#include <hip/hip_runtime.h>

// Involution1d fused: B=16, CH=256, DIM=4096, G=16, GROUP=16, K=7, PAD=3,
// hid=64, K*G=112.  One block = (batch, 64-location tile).
#define BB   16
#define CHN  256
#define DIMN 4096
#define GG   16
#define KK   7
#define PADK 3
#define HID  64
#define KGN  112
#define LT   64          // locations per tile
#define BN_EPS 1e-5f

// ---------------------------------------------------------------------------
// Transpose w1 (64x256 -> w1t 256x64) and w2 (112x64 -> w2t 64x112) so the
// fused kernel reads weight rows as wave-uniform contiguous scalar loads.
__global__ __launch_bounds__(256) void setup_k(
    const float* __restrict__ w1, const float* __restrict__ w2,
    float* __restrict__ w1t, float* __restrict__ w2t) {
    int t = blockIdx.x * 256 + threadIdx.x;
    if (t < HID * CHN) {                 // w1t[c][o] = w1[o][c]
        int o = t & (HID - 1);
        int c = t >> 6;
        w1t[c * HID + o] = w1[o * CHN + c];
    }
    int u = t - HID * CHN;
    if (u >= 0 && u < KGN * HID) {       // w2t[h][r] = w2[r][h]
        int r = u % KGN;
        int h = u / KGN;
        w2t[h * KGN + r] = w2[r * HID + h];
    }
}

// ---------------------------------------------------------------------------
__global__ __launch_bounds__(256) void inv_fused_k(
    const float* __restrict__ x,
    const float* __restrict__ w1t,       // [256][64]
    const float* __restrict__ b1,
    const float* __restrict__ bn_gamma,
    const float* __restrict__ bn_beta,
    const float* __restrict__ bn_mean,
    const float* __restrict__ bn_var,
    const float* __restrict__ w2t,       // [64][112]
    const float* __restrict__ b2,
    float* __restrict__ out) {
    __shared__ float hs[HID][LT];        // 16 KiB
    __shared__ float ks[KGN][LT];        // 28 KiB

    const int t    = threadIdx.x;
    const int l    = t & 63;                                   // lane = location
    const int w    = __builtin_amdgcn_readfirstlane(t >> 6);   // wave id 0..3
    const int tile = blockIdx.x & 63;
    const int b    = blockIdx.x >> 6;
    const int l0   = tile * LT;

    const float* xb = x + (size_t)b * CHN * DIMN + l0 + l;

    // ---- Phase 1: h[o][l] = BN(relu(W1 x + b1)), wave w owns o in [16w,16w+16)
    const int o0 = __builtin_amdgcn_readfirstlane(w * 16);
    float acc[16];
#pragma unroll
    for (int j = 0; j < 16; ++j) acc[j] = b1[o0 + j];

#pragma unroll 8
    for (int c = 0; c < CHN; ++c) {
        float xv = xb[(size_t)c * DIMN];
        const float* wr = w1t + c * HID + o0;
#pragma unroll
        for (int j = 0; j < 16; ++j) acc[j] = fmaf(wr[j], xv, acc[j]);
    }

#pragma unroll
    for (int j = 0; j < 16; ++j) {
        int o = o0 + j;
        float sc = bn_gamma[o] * rsqrtf(bn_var[o] + BN_EPS);
        float sh = bn_beta[o] - bn_mean[o] * sc;
        hs[o][l] = fmaxf(acc[j], 0.0f) * sc + sh;
    }
    __syncthreads();

    // ---- Phase 2: kern[r][l] = W2 h + b2, wave w owns r in [28w, 28w+28)
    const int r0 = __builtin_amdgcn_readfirstlane(w * 28);
    float acc2[28];
#pragma unroll
    for (int j = 0; j < 28; ++j) acc2[j] = b2[r0 + j];

#pragma unroll 4
    for (int hh = 0; hh < HID; ++hh) {
        float hv = hs[hh][l];
        const float* wr2 = w2t + hh * KGN + r0;
#pragma unroll
        for (int j = 0; j < 28; ++j) acc2[j] = fmaf(wr2[j], hv, acc2[j]);
    }

#pragma unroll
    for (int j = 0; j < 28; ++j) ks[r0 + j][l] = acc2[j];
    __syncthreads();

    // ---- Phase 3: involution.  Wave w owns channels [64w, 64w+64) = 4 groups.
    const int g0 = __builtin_amdgcn_readfirstlane(w * 4);
#pragma unroll
    for (int gq = 0; gq < 4; ++gq) {
        int g = g0 + gq;
        float kv[KK];
#pragma unroll
        for (int k = 0; k < KK; ++k) kv[k] = ks[g * KK + k][l];

        for (int ci = 0; ci < 16; ++ci) {
            int ch = g * 16 + ci;
            const float* xrow = x + ((size_t)b * CHN + ch) * DIMN;
            float o = 0.0f;
#pragma unroll
            for (int k = 0; k < KK; ++k) {
                int xi = l0 + l + k - PADK;
                float xv = ((unsigned)xi < (unsigned)DIMN) ? xrow[xi] : 0.0f;
                o = fmaf(kv[k], xv, o);
            }
            out[((size_t)b * CHN + ch) * DIMN + l0 + l] = o;
        }
    }
}

// ---------------------------------------------------------------------------
extern "C" void kernel_launch(void* const* d_in, const int* in_sizes, int n_in,
                              void* d_out, int out_size, void* d_ws, size_t ws_size,
                              hipStream_t stream) {
    (void)in_sizes; (void)n_in; (void)out_size; (void)ws_size;

    const float* x        = (const float*)d_in[0];
    const float* w1       = (const float*)d_in[1];
    const float* b1       = (const float*)d_in[2];
    const float* bn_gamma = (const float*)d_in[3];
    const float* bn_beta  = (const float*)d_in[4];
    const float* bn_mean  = (const float*)d_in[5];
    const float* bn_var   = (const float*)d_in[6];
    const float* w2       = (const float*)d_in[7];
    const float* b2       = (const float*)d_in[8];
    float*       out      = (float*)d_out;

    float* w1t = (float*)d_ws;                 // 256*64 floats
    float* w2t = (float*)d_ws + CHN * HID;     // 64*112 floats

    setup_k<<<(HID * CHN + KGN * HID + 255) / 256, 256, 0, stream>>>(w1, w2, w1t, w2t);
    inv_fused_k<<<BB * (DIMN / LT), 256, 0, stream>>>(
        x, w1t, b1, bn_gamma, bn_beta, bn_mean, bn_var, w2t, b2, out);
}

// Round 4
// 91.779 us; speedup vs baseline: 3.1244x; 1.4953x over previous
//
#include <hip/hip_runtime.h>

// Involution1d: B=16, CH=256, DIM=4096, G=16, K=7, PAD=3, hid=64, K*G=112.
// Split: setup (pack weights to f16 pairs) -> kerngen (fdot2 GEMMs, kern as
// f16 pairs in ws) -> involution (memory-bound, f32 out).
#define BB   16
#define CHN  256
#define DIMN 4096
#define GG   16
#define KK   7
#define PADK 3
#define HID  64
#define KGN  112
#define LT   64
#define CP   (CHN/2)   // 128 c-pairs
#define HP   (HID/2)   // 32  h-pairs
#define RP   (KGN/2)   // 56  r-pairs
#define BN_EPS 1e-5f

typedef __fp16 half2_t __attribute__((ext_vector_type(2)));
union U32H2 { unsigned int u; half2_t h; };

static __device__ inline unsigned int packf(float a, float b) {
    U32H2 t; t.h = __builtin_amdgcn_cvt_pkrtz(a, b); return t.u;
}
static __device__ inline half2_t ash2(unsigned int u) { U32H2 t; t.u = u; return t.h; }
static __device__ inline float dot2(unsigned int a, unsigned int b, float c) {
#if __has_builtin(__builtin_amdgcn_fdot2)
    return __builtin_amdgcn_fdot2(ash2(a), ash2(b), c, false);
#else
    half2_t p = ash2(a), q = ash2(b);
    return c + (float)p[0] * (float)q[0] + (float)p[1] * (float)q[1];
#endif
}

// ---------------------------------------------------------------------------
// Pack w1 (64x256) -> w1p[cp][o] = (w1[o][2cp], w1[o][2cp+1])  [128][64]
// Pack w2 (112x64) -> w2p[hp][r] = (w2[r][2hp], w2[r][2hp+1])  [32][112]
__global__ __launch_bounds__(256) void setup_k(
    const float* __restrict__ w1, const float* __restrict__ w2,
    unsigned int* __restrict__ w1p, unsigned int* __restrict__ w2p) {
    int t = blockIdx.x * 256 + threadIdx.x;
    if (t < CP * HID) {
        int o = t & 63, cp = t >> 6;
        w1p[t] = packf(w1[o * CHN + 2 * cp], w1[o * CHN + 2 * cp + 1]);
    }
    int u = t - CP * HID;
    if (u >= 0 && u < HP * KGN) {
        int r = u % KGN, hp = u / KGN;
        w2p[u] = packf(w2[r * HID + 2 * hp], w2[r * HID + 2 * hp + 1]);
    }
}

// ---------------------------------------------------------------------------
// Kernel generator. Block = (b, 64-location tile), 4 waves; wave w owns
// o in [16w,16w+16) for phase 1 and r in [28w,28w+28) for phase 2.
__global__ __launch_bounds__(256) void kerngen_k(
    const float* __restrict__ x,
    const unsigned int* __restrict__ w1p_g,
    const float* __restrict__ b1,
    const float* __restrict__ bn_gamma,
    const float* __restrict__ bn_beta,
    const float* __restrict__ bn_mean,
    const float* __restrict__ bn_var,
    const unsigned int* __restrict__ w2p_g,
    const float* __restrict__ b2,
    unsigned int* __restrict__ kern) {         // [16][56][4096] u32 (f16 pairs)
    __shared__ unsigned int lw1[CP * HID];     // 32 KiB
    __shared__ unsigned int lhs[HP * LT];      // 8 KiB   (total 40 KiB -> 4 blk/CU)

    const int t  = threadIdx.x;
    const int l  = t & 63;
    const int w  = t >> 6;
    const int b  = blockIdx.x >> 6;
    const int l0 = (blockIdx.x & 63) * LT;

    // stage w1 pairs into LDS (32 KiB, coalesced float4 copies)
    {
        const float4* s1 = (const float4*)w1p_g;
        float4*       d1 = (float4*)lw1;
#pragma unroll
        for (int i = 0; i < (CP * HID / 4) / 256; ++i)   // 8 iters
            d1[t + 256 * i] = s1[t + 256 * i];
    }
    __syncthreads();

    // ---- Phase 1: h = BN(relu(W1 x + b1)) via f16 dot2
    const int o0 = w * 16;
    float acc[16];
#pragma unroll
    for (int j = 0; j < 16; ++j) acc[j] = b1[o0 + j];

    const float* xb = x + (size_t)b * CHN * DIMN + l0 + l;
#pragma unroll 4
    for (int cp = 0; cp < CP; ++cp) {
        float xa = xb[(size_t)(2 * cp) * DIMN];
        float xc = xb[(size_t)(2 * cp + 1) * DIMN];
        unsigned int xp = packf(xa, xc);
        const unsigned int* wr = lw1 + cp * HID + o0;
#pragma unroll
        for (int j = 0; j < 16; ++j) acc[j] = dot2(xp, wr[j], acc[j]);
    }

    float hv[16];
#pragma unroll
    for (int j = 0; j < 16; ++j) {
        int o = o0 + j;
        float sc = bn_gamma[o] * rsqrtf(bn_var[o] + BN_EPS);
        float sh = bn_beta[o] - bn_mean[o] * sc;
        hv[j] = fmaxf(acc[j], 0.0f) * sc + sh;
    }
#pragma unroll
    for (int jj = 0; jj < 8; ++jj)
        lhs[(8 * w + jj) * LT + l] = packf(hv[2 * jj], hv[2 * jj + 1]);
    __syncthreads();

    // ---- Phase 2: kern = W2 h + b2 via f16 dot2 (w2 pairs: uniform global,
    // L1-hot; merged to dwordx4 broadcasts)
    const int r0 = w * 28;
    float acc2[28];
#pragma unroll
    for (int j = 0; j < 28; ++j) acc2[j] = b2[r0 + j];

#pragma unroll 2
    for (int hp = 0; hp < HP; ++hp) {
        unsigned int hp2 = lhs[hp * LT + l];
        const unsigned int* wr2 = w2p_g + hp * KGN + r0;
#pragma unroll
        for (int j = 0; j < 28; ++j) acc2[j] = dot2(hp2, wr2[j], acc2[j]);
    }

    // store kern as f16 pairs over r: row rp = 14w + j
    unsigned int* kb = kern + ((size_t)b * RP + 14 * w) * DIMN + l0 + l;
#pragma unroll
    for (int j = 0; j < 14; ++j)
        kb[(size_t)j * DIMN] = packf(acc2[2 * j], acc2[2 * j + 1]);
}

// ---------------------------------------------------------------------------
// kv extraction: row pair index i and half h for tap k, given group parity.
template <int OFF>
static __device__ inline void extract_kv(const uint4 q[4], float kv[KK][4]) {
#pragma unroll
    for (int k = 0; k < KK; ++k) {
        const int kk = k + OFF;
        const int i  = kk >> 1;
        const int h  = kk & 1;
#pragma unroll
        for (int j = 0; j < 4; ++j) {
            unsigned int u = (&q[i].x)[j];
            half2_t hh = ash2(u);
            kv[k][j] = h ? (float)hh[1] : (float)hh[0];
        }
    }
}

// Involution: one thread per (b, ch, l-quad). kern from packed f16 pairs.
__global__ __launch_bounds__(256) void involution_k(
    const float* __restrict__ x,
    const unsigned int* __restrict__ kern,
    float* __restrict__ out) {
    int t  = blockIdx.x * 256 + threadIdx.x;   // 0 .. 4,194,303
    int lq = t & 1023;
    int ch = (t >> 10) & 255;
    int b  = t >> 18;
    int l  = lq * 4;
    int g  = ch >> 4;                           // wave-uniform

    int rbase = (7 * g) >> 1;
    const unsigned int* kb = kern + ((size_t)b * RP + rbase) * DIMN + l;
    uint4 q[4];
#pragma unroll
    for (int i = 0; i < 4; ++i) q[i] = *(const uint4*)(kb + (size_t)i * DIMN);

    float kv[KK][4];
    if (g & 1) extract_kv<1>(q, kv);
    else       extract_kv<0>(q, kv);

    const float* xrow = x + ((size_t)b * CHN + ch) * DIMN;
    float4 fa = *(const float4*)(xrow + (l > 0 ? l - 4 : 0));
    float4 fb = *(const float4*)(xrow + l);
    float4 fc = *(const float4*)(xrow + (l + 4 < DIMN ? l + 4 : DIMN - 4));

    float xr[10] = { fa.y, fa.z, fa.w, fb.x, fb.y, fb.z, fb.w, fc.x, fc.y, fc.z };
    if (l == 0)        { xr[0] = 0.f; xr[1] = 0.f; xr[2] = 0.f; }
    if (l == DIMN - 4) { xr[7] = 0.f; xr[8] = 0.f; xr[9] = 0.f; }

    float o0 = 0.f, o1 = 0.f, o2 = 0.f, o3 = 0.f;
#pragma unroll
    for (int k = 0; k < KK; ++k) {
        o0 = fmaf(kv[k][0], xr[k + 0], o0);
        o1 = fmaf(kv[k][1], xr[k + 1], o1);
        o2 = fmaf(kv[k][2], xr[k + 2], o2);
        o3 = fmaf(kv[k][3], xr[k + 3], o3);
    }
    *(float4*)(out + ((size_t)b * CHN + ch) * DIMN + l) = make_float4(o0, o1, o2, o3);
}

// ---------------------------------------------------------------------------
extern "C" void kernel_launch(void* const* d_in, const int* in_sizes, int n_in,
                              void* d_out, int out_size, void* d_ws, size_t ws_size,
                              hipStream_t stream) {
    (void)in_sizes; (void)n_in; (void)out_size; (void)ws_size;

    const float* x        = (const float*)d_in[0];
    const float* w1       = (const float*)d_in[1];
    const float* b1       = (const float*)d_in[2];
    const float* bn_gamma = (const float*)d_in[3];
    const float* bn_beta  = (const float*)d_in[4];
    const float* bn_mean  = (const float*)d_in[5];
    const float* bn_var   = (const float*)d_in[6];
    const float* w2       = (const float*)d_in[7];
    const float* b2       = (const float*)d_in[8];
    float*       out      = (float*)d_out;

    unsigned int* w1p  = (unsigned int*)d_ws;        // 8192 u32
    unsigned int* w2p  = w1p + CP * HID;             // 3584 u32
    unsigned int* kern = w2p + HP * KGN;             // 16*56*4096 u32 = 14 MiB

    setup_k<<<(CP * HID + HP * KGN + 255) / 256, 256, 0, stream>>>(w1, w2, w1p, w2p);
    kerngen_k<<<BB * (DIMN / LT), 256, 0, stream>>>(
        x, w1p, b1, bn_gamma, bn_beta, bn_mean, bn_var, w2p, b2, kern);
    involution_k<<<(BB * CHN * (DIMN / 4)) / 256, 256, 0, stream>>>(x, kern, out);
}

// Round 5
// 81.965 us; speedup vs baseline: 3.4985x; 1.1197x over previous
//
#include <hip/hip_runtime.h>

// Involution1d: B=16, CH=256, DIM=4096, G=16, K=7, PAD=3, hid=64, K*G=112.
// setup (split weights hi/lo bf16) -> kerngen (MFMA bf16 split-precision,
// kern f16-pairs in ws) -> involution (memory-bound, unchanged).
#define BB   16
#define CHN  256
#define DIMN 4096
#define KK   7
#define PADK 3
#define HID  64
#define KGN  112
#define RP   56        // kern rows as f16-pairs
#define LT   64        // locations per block tile
#define BN_EPS 1e-5f

typedef __fp16 half2_t __attribute__((ext_vector_type(2)));
typedef short  short8  __attribute__((ext_vector_type(8)));
typedef float  f32x4   __attribute__((ext_vector_type(4)));

union U32H2 { unsigned int u; half2_t h; };

static __device__ __forceinline__ unsigned int packf(float a, float b) {
    U32H2 t; t.h = __builtin_amdgcn_cvt_pkrtz(a, b); return t.u;
}
static __device__ __forceinline__ half2_t ash2(unsigned int u) { U32H2 t; t.u = u; return t.h; }
static __device__ __forceinline__ unsigned short bch(__bf16 h) {
    return __builtin_bit_cast(unsigned short, h);
}

// ---------------------------------------------------------------------------
// Split w1 [64][256] and w2 [112][64] into hi/lo bf16 (row-major, unchanged
// layout); precompute BN scale/shift.
__global__ __launch_bounds__(256) void setup_k(
    const float* __restrict__ w1, const float* __restrict__ w2,
    const float* __restrict__ bn_gamma, const float* __restrict__ bn_beta,
    const float* __restrict__ bn_mean,  const float* __restrict__ bn_var,
    unsigned short* __restrict__ w1hi, unsigned short* __restrict__ w1lo,
    unsigned short* __restrict__ w2hi, unsigned short* __restrict__ w2lo,
    float* __restrict__ scb, float* __restrict__ shb) {
    int t = blockIdx.x * 256 + threadIdx.x;   // grid covers 16384
    if (t < HID * CHN) {
        float f = w1[t];
        __bf16 hi = (__bf16)f;
        w1hi[t] = bch(hi);
        w1lo[t] = bch((__bf16)(f - (float)hi));
    }
    if (t < KGN * HID) {
        float f = w2[t];
        __bf16 hi = (__bf16)f;
        w2hi[t] = bch(hi);
        w2lo[t] = bch((__bf16)(f - (float)hi));
    }
    if (t < HID) {
        float s = bn_gamma[t] * rsqrtf(bn_var[t] + BN_EPS);
        scb[t] = s;
        shb[t] = bn_beta[t] - bn_mean[t] * s;
    }
}

// ---------------------------------------------------------------------------
// MFMA kernel generator.  Block = (b, 64-loc tile), 4 waves; wave w owns
// columns [16w, 16w+16).  Fragment maps (16x16x32 bf16):
//   A[m][k]: m = lane&15, k = 8*(lane>>4) + j
//   B[k][n]: n = lane&15, k = 8*(lane>>4) + j
//   D[m][n]: n = lane&15, m = 4*(lane>>4) + reg
__global__ __launch_bounds__(256) void kerngen_k(
    const float* __restrict__ x,
    const unsigned short* __restrict__ w1hi, const unsigned short* __restrict__ w1lo,
    const float* __restrict__ b1,
    const float* __restrict__ scb, const float* __restrict__ shb,
    const unsigned short* __restrict__ w2hi, const unsigned short* __restrict__ w2lo,
    const float* __restrict__ b2,
    unsigned int* __restrict__ kern) {        // [16][56][4096] f16-pairs
    __shared__ unsigned short hhi[LT * HID];  // 8 KiB  [col][o ^ swz]
    __shared__ unsigned short hlo[LT * HID];  // 8 KiB

    const int t    = threadIdx.x;
    const int lr   = t & 15;          // fragment row/col index
    const int lg   = (t >> 4) & 3;    // k-group
    const int w    = t >> 6;          // wave id
    const int b    = blockIdx.x >> 6;
    const int l0   = (blockIdx.x & 63) * LT;
    const int col  = 16 * w + lr;     // column within block tile (0..63)
    const int gcol = l0 + col;        // global location

    const float* xb = x + (size_t)b * CHN * DIMN + gcol;

    // ---- Phase 1: h = w1 . x  (4 o-frags x 8 k-steps, split bf16) ----
    f32x4 acc[4];
#pragma unroll
    for (int of = 0; of < 4; ++of) acc[of] = (f32x4){0.f, 0.f, 0.f, 0.f};

#pragma unroll
    for (int half = 0; half < 2; ++half) {
        // 32 independent x loads (4 k-steps worth) for MLP
        float xv[4][8];
#pragma unroll
        for (int k4 = 0; k4 < 4; ++k4)
#pragma unroll
            for (int j = 0; j < 8; ++j)
                xv[k4][j] = xb[(size_t)(128 * half + 32 * k4 + 8 * lg + j) * DIMN];

#pragma unroll
        for (int k4 = 0; k4 < 4; ++k4) {
            const int ks = 4 * half + k4;
            short8 bhi, blo;
#pragma unroll
            for (int j = 0; j < 8; ++j) {
                float f = xv[k4][j];
                __bf16 hi = (__bf16)f;
                bhi[j] = (short)bch(hi);
                blo[j] = (short)bch((__bf16)(f - (float)hi));
            }
#pragma unroll
            for (int of = 0; of < 4; ++of) {
                const int aoff = (16 * of + lr) * CHN + 32 * ks + 8 * lg;
                short8 ahi = *(const short8*)(w1hi + aoff);
                short8 alo = *(const short8*)(w1lo + aoff);
                acc[of] = __builtin_amdgcn_mfma_f32_16x16x32_bf16(ahi, bhi, acc[of], 0, 0, 0);
                acc[of] = __builtin_amdgcn_mfma_f32_16x16x32_bf16(ahi, blo, acc[of], 0, 0, 0);
                acc[of] = __builtin_amdgcn_mfma_f32_16x16x32_bf16(alo, bhi, acc[of], 0, 0, 0);
            }
        }
    }

    // ---- bias + relu + BN, then h -> LDS (bf16 hi/lo, swizzled transpose)
#pragma unroll
    for (int of = 0; of < 4; ++of) {
#pragma unroll
        for (int p = 0; p < 2; ++p) {
            const int ov = 16 * of + 4 * lg + 2 * p;
            float h0 = fmaxf(acc[of][2 * p + 0] + b1[ov + 0], 0.f) * scb[ov + 0] + shb[ov + 0];
            float h1 = fmaxf(acc[of][2 * p + 1] + b1[ov + 1], 0.f) * scb[ov + 1] + shb[ov + 1];
            __bf16 h0h = (__bf16)h0; __bf16 h0l = (__bf16)(h0 - (float)h0h);
            __bf16 h1h = (__bf16)h1; __bf16 h1l = (__bf16)(h1 - (float)h1h);
            const int oa = ov ^ ((col & 7) << 3);   // bank-spread swizzle
            *(unsigned int*)&hhi[col * HID + oa] =
                ((unsigned int)bch(h1h) << 16) | bch(h0h);
            *(unsigned int*)&hlo[col * HID + oa] =
                ((unsigned int)bch(h1l) << 16) | bch(h0l);
        }
    }
    // h is produced and consumed by the same wave -> no __syncthreads needed.

    // ---- Phase 2: kern = w2 . h  (7 r-frags x 2 k-steps, split bf16) ----
    f32x4 acc2[7];
#pragma unroll
    for (int rf = 0; rf < 7; ++rf) acc2[rf] = (f32x4){0.f, 0.f, 0.f, 0.f};

#pragma unroll
    for (int ks = 0; ks < 2; ++ks) {
        const int oa = (32 * ks + 8 * lg) ^ ((col & 7) << 3);
        short8 bhi = *(const short8*)&hhi[col * HID + oa];
        short8 blo = *(const short8*)&hlo[col * HID + oa];
#pragma unroll
        for (int rf = 0; rf < 7; ++rf) {
            const int aoff = (16 * rf + lr) * HID + 32 * ks + 8 * lg;
            short8 ahi = *(const short8*)(w2hi + aoff);
            short8 alo = *(const short8*)(w2lo + aoff);
            acc2[rf] = __builtin_amdgcn_mfma_f32_16x16x32_bf16(ahi, bhi, acc2[rf], 0, 0, 0);
            acc2[rf] = __builtin_amdgcn_mfma_f32_16x16x32_bf16(ahi, blo, acc2[rf], 0, 0, 0);
            acc2[rf] = __builtin_amdgcn_mfma_f32_16x16x32_bf16(alo, bhi, acc2[rf], 0, 0, 0);
        }
    }

    // ---- bias + pack f16 pairs + store: r = 16rf + 4lg + {0..3}, col gcol
    unsigned int* kb = kern + (size_t)b * RP * DIMN + gcol;
#pragma unroll
    for (int rf = 0; rf < 7; ++rf) {
#pragma unroll
        for (int p = 0; p < 2; ++p) {
            const int r0 = 16 * rf + 4 * lg + 2 * p;
            float k0 = acc2[rf][2 * p + 0] + b2[r0 + 0];
            float k1 = acc2[rf][2 * p + 1] + b2[r0 + 1];
            kb[(size_t)(r0 >> 1) * DIMN] = packf(k0, k1);
        }
    }
}

// ---------------------------------------------------------------------------
// kv extraction: row pair index i and half h for tap k, given group parity.
template <int OFF>
static __device__ inline void extract_kv(const uint4 q[4], float kv[KK][4]) {
#pragma unroll
    for (int k = 0; k < KK; ++k) {
        const int kk = k + OFF;
        const int i  = kk >> 1;
        const int h  = kk & 1;
#pragma unroll
        for (int j = 0; j < 4; ++j) {
            unsigned int u = (&q[i].x)[j];
            half2_t hh = ash2(u);
            kv[k][j] = h ? (float)hh[1] : (float)hh[0];
        }
    }
}

// Involution: one thread per (b, ch, l-quad). kern from packed f16 pairs.
__global__ __launch_bounds__(256) void involution_k(
    const float* __restrict__ x,
    const unsigned int* __restrict__ kern,
    float* __restrict__ out) {
    int t  = blockIdx.x * 256 + threadIdx.x;   // 0 .. 4,194,303
    int lq = t & 1023;
    int ch = (t >> 10) & 255;
    int b  = t >> 18;
    int l  = lq * 4;
    int g  = ch >> 4;                           // wave-uniform

    int rbase = (7 * g) >> 1;
    const unsigned int* kb = kern + ((size_t)b * RP + rbase) * DIMN + l;
    uint4 q[4];
#pragma unroll
    for (int i = 0; i < 4; ++i) q[i] = *(const uint4*)(kb + (size_t)i * DIMN);

    float kv[KK][4];
    if (g & 1) extract_kv<1>(q, kv);
    else       extract_kv<0>(q, kv);

    const float* xrow = x + ((size_t)b * CHN + ch) * DIMN;
    float4 fa = *(const float4*)(xrow + (l > 0 ? l - 4 : 0));
    float4 fb = *(const float4*)(xrow + l);
    float4 fc = *(const float4*)(xrow + (l + 4 < DIMN ? l + 4 : DIMN - 4));

    float xr[10] = { fa.y, fa.z, fa.w, fb.x, fb.y, fb.z, fb.w, fc.x, fc.y, fc.z };
    if (l == 0)        { xr[0] = 0.f; xr[1] = 0.f; xr[2] = 0.f; }
    if (l == DIMN - 4) { xr[7] = 0.f; xr[8] = 0.f; xr[9] = 0.f; }

    float o0 = 0.f, o1 = 0.f, o2 = 0.f, o3 = 0.f;
#pragma unroll
    for (int k = 0; k < KK; ++k) {
        o0 = fmaf(kv[k][0], xr[k + 0], o0);
        o1 = fmaf(kv[k][1], xr[k + 1], o1);
        o2 = fmaf(kv[k][2], xr[k + 2], o2);
        o3 = fmaf(kv[k][3], xr[k + 3], o3);
    }
    *(float4*)(out + ((size_t)b * CHN + ch) * DIMN + l) = make_float4(o0, o1, o2, o3);
}

// ---------------------------------------------------------------------------
extern "C" void kernel_launch(void* const* d_in, const int* in_sizes, int n_in,
                              void* d_out, int out_size, void* d_ws, size_t ws_size,
                              hipStream_t stream) {
    (void)in_sizes; (void)n_in; (void)out_size; (void)ws_size;

    const float* x        = (const float*)d_in[0];
    const float* w1       = (const float*)d_in[1];
    const float* b1       = (const float*)d_in[2];
    const float* bn_gamma = (const float*)d_in[3];
    const float* bn_beta  = (const float*)d_in[4];
    const float* bn_mean  = (const float*)d_in[5];
    const float* bn_var   = (const float*)d_in[6];
    const float* w2       = (const float*)d_in[7];
    const float* b2       = (const float*)d_in[8];
    float*       out      = (float*)d_out;

    unsigned short* w1hi = (unsigned short*)d_ws;          // 16384
    unsigned short* w1lo = w1hi + HID * CHN;               // 16384
    unsigned short* w2hi = w1lo + HID * CHN;               // 7168
    unsigned short* w2lo = w2hi + KGN * HID;               // 7168
    float*          scb  = (float*)(w2lo + KGN * HID);     // 64
    float*          shb  = scb + HID;                      // 64
    unsigned int*   kern = (unsigned int*)(shb + HID);     // 16*56*4096 = 14 MiB

    setup_k<<<(HID * CHN + 255) / 256, 256, 0, stream>>>(
        w1, w2, bn_gamma, bn_beta, bn_mean, bn_var,
        w1hi, w1lo, w2hi, w2lo, scb, shb);
    kerngen_k<<<BB * (DIMN / LT), 256, 0, stream>>>(
        x, w1hi, w1lo, b1, scb, shb, w2hi, w2lo, b2, kern);
    involution_k<<<(BB * CHN * (DIMN / 4)) / 256, 256, 0, stream>>>(x, kern, out);
}